// Round 1
// baseline (193.428 us; speedup 1.0000x reference)
//
#include <hip/hip_runtime.h>
#include <hip/hip_bf16.h>

// Problem constants
#define NB    4096      // batch rows
#define IND_  512       // feature dim (GEMM K)
#define OUTD_ 512       // output dim (GEMM M, "o")
#define XCOLS 514       // P + IND
#define ND    25        // D^P

// GEMM tiling
#define BM 128          // o-tile
#define BN 128          // b-tile
#define BK 64

typedef float  f32x4  __attribute__((ext_vector_type(4)));
typedef __bf16 bf16x8 __attribute__((ext_vector_type(8)));
typedef unsigned short u16x8 __attribute__((ext_vector_type(8)));

__device__ __forceinline__ unsigned short f2bf(float f) {
  // round-to-nearest-even fp32 -> bf16 (inputs are finite, in [0,1))
  unsigned int x = __float_as_uint(f);
  return (unsigned short)((x + 0x7fffu + ((x >> 16) & 1u)) >> 16);
}

__device__ __forceinline__ float basis_f(float t, int j) {
  switch (j) {
    case 0: return 1.0f;
    case 1: return t;
    case 2: return t * t;
    case 3: { float r = t - 0.33f; r = r > 0.0f ? r : 0.0f; return r * r; }
    default:{ float r = t - 0.66f; r = r > 0.0f ? r : 0.0f; return r * r; }
  }
}

__device__ __forceinline__ void gload_lds16(const void* g, void* l) {
  __builtin_amdgcn_global_load_lds(
      (const __attribute__((address_space(1))) void*)g,
      (__attribute__((address_space(3))) void*)l, 16, 0, 0);
}

// ---------------------------------------------------------------------------
// prep_x: per row b: kb[b][25], XFb[b][i] (bf16), out[b][0:2] = x_treat
// grid 1024 x 256 threads (4 rows/block, 1 wave per row)
// ---------------------------------------------------------------------------
__global__ __launch_bounds__(256) void prep_x_kernel(
    const float* __restrict__ x, unsigned short* __restrict__ XFb,
    float* __restrict__ kb, float* __restrict__ out)
{
  const int b    = blockIdx.x * 4 + (threadIdx.x >> 6);
  const int lane = threadIdx.x & 63;
  const float* xr = x + (size_t)b * XCOLS;

  // 8 features per lane; base offset 2 floats => only 8B aligned -> float2
  const float* fp = xr + 2 + lane * 8;
  float2 a0 = *(const float2*)(fp + 0);
  float2 a1 = *(const float2*)(fp + 2);
  float2 a2 = *(const float2*)(fp + 4);
  float2 a3 = *(const float2*)(fp + 6);
  u16x8 pk;
  pk[0] = f2bf(a0.x); pk[1] = f2bf(a0.y); pk[2] = f2bf(a1.x); pk[3] = f2bf(a1.y);
  pk[4] = f2bf(a2.x); pk[5] = f2bf(a2.y); pk[6] = f2bf(a3.x); pk[7] = f2bf(a3.y);
  *reinterpret_cast<u16x8*>(XFb + (size_t)b * IND_ + lane * 8) = pk;

  float t0 = xr[0], t1 = xr[1];
  if (lane < 2) out[(size_t)b * XCOLS + lane] = (lane == 0) ? t0 : t1;
  if (lane < ND) {
    int d1 = lane / 5;
    int d2 = lane - d1 * 5;
    kb[(size_t)b * ND + lane] = basis_f(t0, d1) * basis_f(t1, d2);
  }
}

// ---------------------------------------------------------------------------
// prep_w: W[i,o,d] (fp32) -> Wt[(d*512+o)][i] (bf16).  One block per o.
// LDS tile stride 25 words: lanes at stride-25 -> gcd(25,32)=1, conflict-free.
// ---------------------------------------------------------------------------
__global__ __launch_bounds__(256) void prep_w_kernel(
    const float* __restrict__ W, unsigned short* __restrict__ Wt)
{
  __shared__ float tile[IND_ * ND];   // 51200 B
  const int o   = blockIdx.x;
  const int tid = threadIdx.x;

  #pragma unroll
  for (int r = 0; r < 2; ++r) {
    int i = tid + r * 256;
    const float* src = W + ((size_t)i * OUTD_ + o) * ND;   // 25 contiguous floats
    #pragma unroll
    for (int d = 0; d < ND; ++d) tile[i * ND + d] = src[d];
  }
  __syncthreads();
  for (int d = 0; d < ND; ++d) {
    size_t rowb = ((size_t)d * OUTD_ + o) * (size_t)IND_;
    Wt[rowb + tid]       = f2bf(tile[tid * ND + d]);
    Wt[rowb + tid + 256] = f2bf(tile[(tid + 256) * ND + d]);
  }
}

// ---------------------------------------------------------------------------
// gemm: D[m=o][n=b] = sum_d kb[b,d] * sum_i Wt_d[o,i]*XFb[b,i]
// 128x128 tile, BK=64, mfma_f32_16x16x32_bf16, global_load_lds width 16.
// gridDim.z = S splits of the 25 d-phases; partial sums to P[z].
// ---------------------------------------------------------------------------
__global__ __launch_bounds__(256, 2) void gemm_kernel(
    const unsigned short* __restrict__ Wt, const unsigned short* __restrict__ XFb,
    const float* __restrict__ kb, float* __restrict__ P)
{
  __shared__ unsigned short Als[BM * BK];   // [o][k] 16 KB
  __shared__ unsigned short Bls[BN * BK];   // [b][k] 16 KB
  __shared__ float kbls[BN * ND];           // 12.8 KB

  const int tid  = threadIdx.x;
  const int lane = tid & 63;
  const int w    = tid >> 6;
  const int l15  = lane & 15;
  const int quad = lane >> 4;
  const int o0   = blockIdx.x * BM;
  const int b0   = blockIdx.y * BN;
  const int z    = blockIdx.z;
  const int S    = gridDim.z;
  const int d_start = (z * ND) / S;
  const int d_end   = ((z + 1) * ND) / S;

  for (int i = tid; i < BN * ND; i += 256) kbls[i] = kb[(size_t)b0 * ND + i];

  const int o_off = (w & 1) * 64;
  const int b_off = (w >> 1) * 64;
  const int srow  = lane >> 3;        // row within 8-row (1KB) chunk
  const int scol  = (lane & 7) * 8;   // bf16 col within row (16B granules)

  f32x4 acc[4][4], fin[4][4];
  #pragma unroll
  for (int i = 0; i < 4; ++i)
    #pragma unroll
    for (int j = 0; j < 4; ++j) fin[i][j] = (f32x4)0.0f;

  for (int d = d_start; d < d_end; ++d) {
    #pragma unroll
    for (int i = 0; i < 4; ++i)
      #pragma unroll
      for (int j = 0; j < 4; ++j) acc[i][j] = (f32x4)0.0f;

    const size_t arowbase = ((size_t)d * OUTD_ + o0) * (size_t)IND_;

    for (int k0 = 0; k0 < IND_; k0 += BK) {
      // stage A (16KB) + B (16KB): 16 chunks each of 1024B; wave w does 4+4
      #pragma unroll
      for (int c = 0; c < 4; ++c) {
        int chunk = w * 4 + c;
        int r = chunk * 8 + srow;
        const unsigned short* ga = Wt + arowbase + (size_t)r * IND_ + k0 + scol;
        gload_lds16(ga, &Als[chunk * 512]);
        const unsigned short* gb = XFb + (size_t)(b0 + r) * IND_ + k0 + scol;
        gload_lds16(gb, &Bls[chunk * 512]);
      }
      __syncthreads();

      #pragma unroll
      for (int ks = 0; ks < 2; ++ks) {
        bf16x8 af[4], bfr[4];
        #pragma unroll
        for (int mf = 0; mf < 4; ++mf) {
          int row = o_off + mf * 16 + l15;
          af[mf] = *reinterpret_cast<const bf16x8*>(&Als[row * BK + ks * 32 + quad * 8]);
        }
        #pragma unroll
        for (int nf = 0; nf < 4; ++nf) {
          int row = b_off + nf * 16 + l15;
          bfr[nf] = *reinterpret_cast<const bf16x8*>(&Bls[row * BK + ks * 32 + quad * 8]);
        }
        #pragma unroll
        for (int mf = 0; mf < 4; ++mf)
          #pragma unroll
          for (int nf = 0; nf < 4; ++nf)
            acc[mf][nf] = __builtin_amdgcn_mfma_f32_16x16x32_bf16(
                af[mf], bfr[nf], acc[mf][nf], 0, 0, 0);
      }
      __syncthreads();
    }

    // phase end: fin += kb[b,d] * acc ; kb is per-lane (column) constant
    #pragma unroll
    for (int nf = 0; nf < 4; ++nf) {
      float kv = kbls[(b_off + nf * 16 + l15) * ND + d];
      #pragma unroll
      for (int mf = 0; mf < 4; ++mf)
        #pragma unroll
        for (int r = 0; r < 4; ++r)
          fin[mf][nf][r] += kv * acc[mf][nf][r];
    }
  }

  // store partial tile: P[z][b][o]; lane's 4 regs = 4 consecutive o
  float* Pz = P + (size_t)z * NB * OUTD_;
  #pragma unroll
  for (int mf = 0; mf < 4; ++mf)
    #pragma unroll
    for (int nf = 0; nf < 4; ++nf) {
      int bg = b0 + b_off + nf * 16 + l15;
      int og = o0 + o_off + mf * 16 + quad * 4;
      *reinterpret_cast<f32x4*>(&Pz[(size_t)bg * OUTD_ + og]) = fin[mf][nf];
    }
}

// ---------------------------------------------------------------------------
// epilogue: out[b][2+o] = relu(sum_z P[z][b][o] + dot25(kb[b], bias[o]))
// ---------------------------------------------------------------------------
__global__ __launch_bounds__(256) void epilogue_kernel(
    const float* __restrict__ P, const float* __restrict__ kb,
    const float* __restrict__ bias, float* __restrict__ out, int S)
{
  const int idx = blockIdx.x * 256 + threadIdx.x;   // < 4096*512
  const int b = idx >> 9;
  const int o = idx & 511;
  float s = 0.0f;
  for (int zz = 0; zz < S; ++zz) s += P[(size_t)zz * (NB * OUTD_) + idx];
  const float* kr = kb + (size_t)b * ND;
  const float* br = bias + (size_t)o * ND;
  float t = 0.0f;
  #pragma unroll
  for (int d = 0; d < ND; ++d) t += kr[d] * br[d];
  s += t;
  out[(size_t)b * XCOLS + 2 + o] = s > 0.0f ? s : 0.0f;
}

// ---------------------------------------------------------------------------
extern "C" void kernel_launch(void* const* d_in, const int* in_sizes, int n_in,
                              void* d_out, int out_size, void* d_ws, size_t ws_size,
                              hipStream_t stream) {
  const float* x    = (const float*)d_in[0];   // 4096 x 514
  const float* W    = (const float*)d_in[1];   // 512 x 512 x 25
  const float* bias = (const float*)d_in[2];   // 512 x 25
  float* out = (float*)d_out;
  char* ws = (char*)d_ws;

  // ws layout
  const size_t xfb_off = 0;                         // 4096*512*2  = 4,194,304
  const size_t wt_off  = 4194304;                   // 12800*512*2 = 13,107,200
  const size_t kb_off  = 17301504;                  // 4096*25*4   = 409,600
  const size_t p_off   = 17711104;                  // S * 8,388,608
  unsigned short* XFb = (unsigned short*)(ws + xfb_off);
  unsigned short* Wt  = (unsigned short*)(ws + wt_off);
  float* kb           = (float*)(ws + kb_off);
  float* P            = (float*)(ws + p_off);

  int S = 4;
  if (ws_size < p_off + 4ull * 8388608ull) {
    size_t avail = ws_size > p_off ? (ws_size - p_off) / 8388608ull : 1;
    S = (int)(avail < 1 ? 1 : avail);
    if (S > 4) S = 4;
  }

  prep_x_kernel<<<NB / 4, 256, 0, stream>>>(x, XFb, kb, out);
  prep_w_kernel<<<OUTD_, 256, 0, stream>>>(W, Wt);
  gemm_kernel<<<dim3(OUTD_ / BM, NB / BN, S), 256, 0, stream>>>(Wt, XFb, kb, P);
  epilogue_kernel<<<(NB * OUTD_) / 256, 256, 0, stream>>>(P, kb, bias, out, S);
}